// Round 21
// baseline (124.406 us; speedup 1.0000x reference)
//
#include <hip/hip_runtime.h>
#include <hip/hip_bf16.h>

// Problem constants: B=8, N=8192, S=2048, C1=128, C2=256, OUT=256
#define BB   8
#define NN   8192
#define SS   2048
#define C1C  128
#define C2C  256
#define KIN  384
#define OUTC 256

typedef __attribute__((ext_vector_type(4))) float f32x4;
typedef __attribute__((ext_vector_type(8))) short short8;
typedef __attribute__((ext_vector_type(8))) unsigned short ushortx8;

__device__ __forceinline__ ushort f2bf(float v) {
    __hip_bfloat16 h = __float2bfloat16(v);
    return __builtin_bit_cast(ushort, h);
}

__device__ __forceinline__ float med3(float a, float b, float c) {
    return __builtin_amdgcn_fmed3f(a, b, c);
}

// x -> bucket quantizer: 256 bins over [-4,4], clamped. Monotone
// non-decreasing in x, so a bucket-range window provably contains every
// point in an x-interval.
__device__ __forceinline__ int xbucket(float x) {
    int b = (int)floorf((x + 4.0f) * 32.0f);
    return min(max(b, 0), 255);
}

// ---------------------------------------------------------------------------
// Fused 3-NN (x-bucket pruned) + gather + weights prep.
// NEW vs r20: the exhaustive 2x2048-eval scan (measured floor 65.5us,
// VALU-issue-bound) is replaced by windowed selection:
//  1. counting-sort point indices by x into 256 buckets (LDS, O(n));
//  2. per query: seed = exact 3rd-best VALUE over a 256-slot window at the
//     query's bucket (branchless med3; upper bound on final d2_3rd since
//     window subset of full set);
//  3. bucket-range window [px-rx, px+rx], rx = 1.001*sqrt(seed+n1): every
//     point with d2 <= d2_3rd_final <= seed has |dx| <= rx -> inside;
//  4. exact lex (f, orig-idx) top-3 over the window (branchless inserts;
//     scan order arbitrary so full lex == stable lax.top_k). Same fmaf
//     formula on identical bits -> selection identical to passing kernels.
// Evals/query: 4096 -> ~450. 1024 thr, 128 q/block, 512 blocks, 8 w/SIMD.
// ---------------------------------------------------------------------------
__global__ __launch_bounds__(1024, 8) void knn_gather_prep_kernel(
    const float* __restrict__ xyz1, const float* __restrict__ xyz2,
    const float* __restrict__ feat2, ushort* __restrict__ interpB,
    const float* __restrict__ W1, ushort* __restrict__ W1pack,
    const float* __restrict__ W2, ushort* __restrict__ W2pack)
{
    __shared__ float4 sp[SS];                     // 32 KB (original order)
    __shared__ int    ssid[SS];                   // 8 KB: bucket-sorted indices
    __shared__ int    cnt[256];                   // hist -> inclusive prefix
    __shared__ int    cnt2[256];                  // scatter counters
    __shared__ int    sIdx[128][3];
    __shared__ float  sW[128][3];

    const int tid   = threadIdx.x;
    const int b     = blockIdx.x & 7;             // XCD-aligned batch
    const int chunk = blockIdx.x >> 3;            // 0..63
    const int qbase = chunk << 7;                 // 128 queries per block

    if (tid < 256) { cnt[tid] = 0; cnt2[tid] = 0; }
    __syncthreads();

    const float* x2 = xyz2 + (size_t)b * SS * 3;
    for (int i = tid; i < SS; i += 1024) {
        float x = x2[i*3+0], y = x2[i*3+1], z = x2[i*3+2];
        sp[i] = make_float4(-2.f*x, -2.f*y, -2.f*z, x*x + y*y + z*z);
        atomicAdd(&cnt[xbucket(x)], 1);
    }

    // ---- folded weights prep (r20, unchanged): 1 guarded elem/thread -----
    {
        const int idx = blockIdx.x * 1024 + tid;  // 0..524287
        const int n1 = 12 * 16 * 512;             // 98304 (W1pack)
        if (idx < n1) {
            int o = idx;
            int e = o & 7, lane = (o >> 3) & 63, j = (o >> 9) & 3;
            int wc = (o >> 11) & 3, s = o >> 13;
            int n = wc * 64 + j * 16 + (lane & 15);
            int k = s * 32 + (lane >> 4) * 8 + e;
            W1pack[o] = f2bf(W1[(size_t)k * OUTC + n]);
        } else if (idx < n1 + OUTC * OUTC) {
            int o = idx - n1;
            int e = o & 7, lane = (o >> 3) & 63, j = (o >> 9) & 3;
            int wc = (o >> 11) & 3, s = o >> 13;
            int n = wc * 64 + j * 16 + (lane & 15);
            int k = s * 32 + (lane >> 4) * 8 + e;
            W2pack[o] = f2bf(W2[(size_t)k * OUTC + n]);
        }
    }
    __syncthreads();

    // ---- inclusive prefix sum over 256 buckets (Hillis-Steele) -----------
    for (int d = 1; d < 256; d <<= 1) {
        int v = 0;
        if (tid < 256) {
            v = cnt[tid];
            if (tid >= d) v += cnt[tid - d];
        }
        __syncthreads();
        if (tid < 256) cnt[tid] = v;
        __syncthreads();
    }

    // ---- scatter: ssid = indices bucket-sorted by x ----------------------
    for (int i = tid; i < SS; i += 1024) {
        float x = -0.5f * sp[i].x;                // exact (pow2 scales)
        int bq = xbucket(x);
        int base = (bq == 0) ? 0 : cnt[bq - 1];
        int pos = base + atomicAdd(&cnt2[bq], 1);
        ssid[pos] = i;
    }
    __syncthreads();

    const int g = tid >> 4;                       // 0..63 (query pair)
    const int l = tid & 15;                       // lane within query
    const int qa = qbase + g * 2;

    const float* qp = xyz1 + ((size_t)b * NN + qa) * 3;
    float pxa[2] = {qp[0], qp[3]};
    float pya[2] = {qp[1], qp[4]};
    float pza[2] = {qp[2], qp[5]};

#pragma unroll
    for (int qi = 0; qi < 2; ++qi) {
        const float px = pxa[qi], py = pya[qi], pz = pza[qi];
        const float n1 = px*px + py*py + pz*pz;

        // ---- seed pass: 3rd-best VALUE over 256 slots at query's bucket --
        int cb = xbucket(px);
        int c  = (cb == 0) ? 0 : cnt[cb - 1];
        int w0 = min(max(c - 128, 0), SS - 256);
        float a0 = 1e30f, a1 = 1e30f, a2 = 1e30f;
#pragma unroll
        for (int u = 0; u < 16; ++u) {
            int o = ssid[w0 + u * 16 + l];
            float4 P = sp[o];
            float f = fmaf(px, P.x, fmaf(py, P.y, fmaf(pz, P.z, P.w)));
            a2 = med3(f, a1, a2);
            a1 = med3(f, a0, a1);
            a0 = fminf(f, a0);
        }
#pragma unroll
        for (int m = 1; m <= 8; m <<= 1) {
            float b0 = __shfl_xor(a0, m);
            float b1 = __shfl_xor(a1, m);
            float b2 = __shfl_xor(a2, m);
            float bv[3] = {b0, b1, b2};
#pragma unroll
            for (int e = 0; e < 3; ++e) {
                float d = bv[e];
                a2 = med3(d, a1, a2);
                a1 = med3(d, a0, a1);
                a0 = fminf(d, a0);
            }
        }

        // ---- window: all points with |x - px| <= rx ----------------------
        float r2 = fmaxf(a2 + n1, 0.f);
        float rx = sqrtf(r2) * 1.001f;            // margin for fp rounding
        int blo = xbucket(px - rx);
        int bhi = xbucket(px + rx);
        int lo2 = (blo == 0) ? 0 : cnt[blo - 1];
        int ub  = cnt[bhi];

        // ---- exact lex top-3 over the window -----------------------------
        float e0 = 1e30f, e1 = 1e30f, e2 = 1e30f;
        int   i0 = 0x3fffffff, i1 = 0x3fffffff, i2 = 0x3fffffff;
        for (int s0 = lo2; s0 < ub; s0 += 16) {
            int slot = s0 + l;
            if (slot < ub) {
                int o = ssid[slot];
                float4 P = sp[o];
                float f = fmaf(px, P.x, fmaf(py, P.y, fmaf(pz, P.z, P.w)));
                bool lt2 = (f < e2) || (f == e2 && o < i2);
                bool lt1 = (f < e1) || (f == e1 && o < i1);
                bool lt0 = (f < e0) || (f == e0 && o < i0);
                float ne2 = lt1 ? e1 : (lt2 ? f : e2);
                int   ni2 = lt1 ? i1 : (lt2 ? o : i2);
                float ne1 = lt0 ? e0 : (lt1 ? f : e1);
                int   ni1 = lt0 ? i0 : (lt1 ? o : i1);
                float ne0 = lt0 ? f : e0;
                int   ni0 = lt0 ? o : i0;
                e2 = ne2; i2 = ni2; e1 = ne1; i1 = ni1; e0 = ne0; i0 = ni0;
            }
        }

        // lex merge across the 16-lane group
#pragma unroll
        for (int m = 1; m <= 8; m <<= 1) {
            float ob0 = __shfl_xor(e0, m), ob1 = __shfl_xor(e1, m), ob2 = __shfl_xor(e2, m);
            int   oj0 = __shfl_xor(i0, m), oj1 = __shfl_xor(i1, m), oj2 = __shfl_xor(i2, m);
            float dv[3] = {ob0, ob1, ob2}; int iv[3] = {oj0, oj1, oj2};
#pragma unroll
            for (int e = 0; e < 3; ++e) {
                float d = dv[e]; int s = iv[e];
                bool lt2 = (d < e2) || (d == e2 && s < i2);
                bool lt1 = (d < e1) || (d == e1 && s < i1);
                bool lt0 = (d < e0) || (d == e0 && s < i0);
                float ne2 = lt1 ? e1 : (lt2 ? d : e2);
                int   ni2 = lt1 ? i1 : (lt2 ? s : i2);
                float ne1 = lt0 ? e0 : (lt1 ? d : e1);
                int   ni1 = lt0 ? i0 : (lt1 ? s : i1);
                float ne0 = lt0 ? d : e0;
                int   ni0 = lt0 ? s : i0;
                e2 = ne2; i2 = ni2; e1 = ne1; i1 = ni1; e0 = ne0; i0 = ni0;
            }
        }

        if (l == 0) {
            float d0 = sqrtf(fmaxf(n1 + e0, 0.f));
            float d1 = sqrtf(fmaxf(n1 + e1, 0.f));
            float d2s = sqrtf(fmaxf(n1 + e2, 0.f));
            float w0v = 1.f / fmaxf(d0, 1e-10f);
            float w1v = 1.f / fmaxf(d1, 1e-10f);
            float w2v = 1.f / fmaxf(d2s, 1e-10f);
            float wsum = w0v + w1v + w2v;
            int qq = g * 2 + qi;
            sIdx[qq][0] = i0; sIdx[qq][1] = i1; sIdx[qq][2] = i2;
            sW[qq][0] = w0v / wsum; sW[qq][1] = w1v / wsum; sW[qq][2] = w2v / wsum;
        }
    }
    __syncthreads();

    // gather phase: wave wid handles queries wid, wid+16, ... (coalesced rows)
    const int wid = tid >> 6, lane = tid & 63;
    for (int qq = wid; qq < 128; qq += 16) {
        int a0 = sIdx[qq][0], a1 = sIdx[qq][1], a2 = sIdx[qq][2];
        float w0 = sW[qq][0], w1 = sW[qq][1], w2 = sW[qq][2];
        const float4* r0 = (const float4*)(feat2 + ((size_t)b * SS + a0) * C2C);
        const float4* r1 = (const float4*)(feat2 + ((size_t)b * SS + a1) * C2C);
        const float4* r2 = (const float4*)(feat2 + ((size_t)b * SS + a2) * C2C);
        float4 v0 = r0[lane], v1 = r1[lane], v2 = r2[lane];
        ushort4 o;
        o.x = f2bf(w0*v0.x + w1*v1.x + w2*v2.x);
        o.y = f2bf(w0*v0.y + w1*v1.y + w2*v2.y);
        o.z = f2bf(w0*v0.z + w1*v1.z + w2*v2.z);
        o.w = f2bf(w0*v0.w + w1*v1.w + w2*v2.w);
        *(ushort4*)(interpB + ((size_t)b * NN + qbase + qq) * C2C + lane * 4) = o;
    }
}

// ---------------------------------------------------------------------------
// FUSED two-layer MFMA GEMM (EXACT r20, measured best):
//   out = relu(relu([feat1|interpB]@W1^T + b1)@W2^T + b2), H in LDS only.
// Phase 1: A-only LDS dbuf + register-B from W1pack. Phase 2: register-B
// from W2pack, barrier-free.
// ---------------------------------------------------------------------------
#define GBM 128
#define GBN 256
#define GBK 32

__device__ __forceinline__ void gld_lds16(const void* g, void* l) {
    __builtin_amdgcn_global_load_lds(
        (const __attribute__((address_space(1))) void*)g,
        (__attribute__((address_space(3))) void*)l, 16, 0, 0);
}

__global__ __launch_bounds__(512, 4) void gemm_fused(
    const float* __restrict__ feat1,
    const ushort* __restrict__ interpB,
    const ushort* __restrict__ W1pack, const float* __restrict__ b1,
    const ushort* __restrict__ W2pack, const float* __restrict__ b2,
    float* __restrict__ out)
{
    __shared__ ushort pool[GBM * 256];   // 64 KB: phase1 A-dbuf (2x8KB); then H

    const int tid  = threadIdx.x;
    const int lane = tid & 63;
    const int wid  = tid >> 6;           // 0..7
    const int m0   = blockIdx.x * GBM;
    const int wr   = wid >> 2;           // 0..1
    const int wc   = wid & 3;            // 0..3

    const int rsub = lane >> 2;                    // 0..15 (row in 16-row chunk)
    const int slot = lane & 3;                     // 0..3  (8-ushort slot)
    const int csub = slot * 8;                     // linear LDS slot offset
    const int usw  = (slot ^ (rsub & 3)) * 8;      // swizzled SOURCE slot offset

    const int kgrp = (lane >> 4) * 8;
    const int rl   = lane & 15;
    const int ksw  = kgrp ^ ((rl & 3) << 3);       // swizzled read slot
    const int cl   = lane & 15;
    const int rgrp = (lane >> 4) * 4;

    // stage one K-step of A only: each wave stages its own 16-row chunk.
    auto stageA = [&](int k0, int buf) {
        ushort* sAb = pool + buf * 4096;           // 8KB buffer
        const int r = m0 + wid * 16 + rsub;
        if (k0 < C1C) {
            const float* src = feat1 + (size_t)r * C1C + k0 + usw;
            float4 u = ((const float4*)src)[0];
            float4 v = ((const float4*)src)[1];
            ushortx8 t;
            t[0] = f2bf(u.x); t[1] = f2bf(u.y); t[2] = f2bf(u.z); t[3] = f2bf(u.w);
            t[4] = f2bf(v.x); t[5] = f2bf(v.y); t[6] = f2bf(v.z); t[7] = f2bf(v.w);
            *(ushortx8*)&sAb[wid * 512 + rsub * 32 + csub] = t;
        } else {
            gld_lds16(interpB + (size_t)r * C2C + (k0 - C1C) + usw, &sAb[wid * 512]);
        }
    };

    // ---------------- phase 1: acc1 = A @ W1^T (A-dbuf + register B) -------
    f32x4 acc1[4][4];
#pragma unroll
    for (int i = 0; i < 4; ++i)
#pragma unroll
        for (int j = 0; j < 4; ++j) acc1[i][j] = (f32x4){0.f, 0.f, 0.f, 0.f};

    int cur = 0;
    stageA(0, 0);
    short8 bfc[4], bfn[4];
#pragma unroll
    for (int j = 0; j < 4; ++j)
        bfc[j] = *(const short8*)&W1pack[(size_t)(0 * 16 + wc * 4 + j) * 512 + lane * 8];

    for (int k0 = 0, s = 0; k0 < KIN; k0 += GBK, ++s) {
        __syncthreads();                 // stage(k0->cur) done; prev reads done
        if (k0 + GBK < KIN) {
            stageA(k0 + GBK, cur ^ 1);
#pragma unroll
            for (int j = 0; j < 4; ++j)
                bfn[j] = *(const short8*)&W1pack[(size_t)((s + 1) * 16 + wc * 4 + j) * 512 + lane * 8];
        }

        const ushort* sAb = pool + cur * 4096;
        short8 af[4];
#pragma unroll
        for (int i = 0; i < 4; ++i)
            af[i] = *(const short8*)&sAb[(wr * 64 + i * 16 + rl) * GBK + ksw];
#pragma unroll
        for (int i = 0; i < 4; ++i)
#pragma unroll
            for (int j = 0; j < 4; ++j)
                acc1[i][j] = __builtin_amdgcn_mfma_f32_16x16x32_bf16(
                    af[i], bfc[j], acc1[i][j], 0, 0, 0);
#pragma unroll
        for (int j = 0; j < 4; ++j) bfc[j] = bfn[j];
        cur ^= 1;
    }
    __syncthreads();                     // all phase-1 LDS reads done (pool reuse)

    // issue phase-2 first B-frags early (hide L2 latency under H writes)
#pragma unroll
    for (int j = 0; j < 4; ++j)
        bfc[j] = *(const short8*)&W2pack[(size_t)(0 * 16 + wc * 4 + j) * 512 + lane * 8];

    // ---------------- transition: H = relu(acc1+b1) -> LDS (bf16) ----------
#pragma unroll
    for (int j = 0; j < 4; ++j) {
        const int c = wc * 64 + j * 16 + cl;
        const float bv = b1[c];
        const int u = c >> 3, sub = c & 7;
#pragma unroll
        for (int i = 0; i < 4; ++i) {
#pragma unroll
            for (int rr = 0; rr < 4; ++rr) {
                const int r = wr * 64 + i * 16 + rgrp + rr;
                const float v = fmaxf(acc1[i][j][rr] + bv, 0.f);
                pool[r * 256 + ((u ^ (r & 31)) << 3) + sub] = f2bf(v);
            }
        }
    }
    __syncthreads();                     // H complete

    // ---------------- phase 2: out = relu(H @ W2^T + b2), barrier-free -----
    f32x4 acc2[4][4];
#pragma unroll
    for (int i = 0; i < 4; ++i)
#pragma unroll
        for (int j = 0; j < 4; ++j) acc2[i][j] = (f32x4){0.f, 0.f, 0.f, 0.f};

    for (int s = 0; s < 8; ++s) {
        if (s < 7) {
#pragma unroll
            for (int j = 0; j < 4; ++j)
                bfn[j] = *(const short8*)&W2pack[(size_t)((s + 1) * 16 + wc * 4 + j) * 512 + lane * 8];
        }
        const int ub = s * 4 + (lane >> 4);        // H unit index 0..31
        short8 af[4];
#pragma unroll
        for (int i = 0; i < 4; ++i) {
            const int r = wr * 64 + i * 16 + rl;
            af[i] = *(const short8*)&pool[r * 256 + ((ub ^ (r & 31)) << 3)];
        }
#pragma unroll
        for (int i = 0; i < 4; ++i)
#pragma unroll
            for (int j = 0; j < 4; ++j)
                acc2[i][j] = __builtin_amdgcn_mfma_f32_16x16x32_bf16(
                    af[i], bfc[j], acc2[i][j], 0, 0, 0);
#pragma unroll
        for (int j = 0; j < 4; ++j) bfc[j] = bfn[j];
    }

    // ---------------- epilogue: bias + relu -> f32 out ---------------------
#pragma unroll
    for (int j = 0; j < 4; ++j) {
        const int col = wc * 64 + j * 16 + cl;
        const float bv = b2[col];
#pragma unroll
        for (int i = 0; i < 4; ++i) {
            const int rowb = m0 + wr * 64 + i * 16 + rgrp;
#pragma unroll
            for (int rr = 0; rr < 4; ++rr) {
                out[(size_t)(rowb + rr) * OUTC + col] =
                    fmaxf(acc2[i][j][rr] + bv, 0.f);
            }
        }
    }
}

// ---------------------------------------------------------------------------
// ws layout (bytes): interpB 33.5M @0 | W1pack 192K @33554432
// | W2pack 128K @33751040
// ---------------------------------------------------------------------------
extern "C" void kernel_launch(void* const* d_in, const int* in_sizes, int n_in,
                              void* d_out, int out_size, void* d_ws, size_t ws_size,
                              hipStream_t stream) {
    const float* xyz1  = (const float*)d_in[0];
    const float* xyz2  = (const float*)d_in[1];
    const float* feat1 = (const float*)d_in[2];
    const float* feat2 = (const float*)d_in[3];
    const float* W1    = (const float*)d_in[4];
    const float* b1    = (const float*)d_in[5];
    const float* W2    = (const float*)d_in[6];
    const float* b2    = (const float*)d_in[7];
    float* out = (float*)d_out;

    char* ws = (char*)d_ws;
    ushort* interpB = (ushort*)(ws);
    ushort* W1pack  = (ushort*)(ws + 33554432);
    ushort* W2pack  = (ushort*)(ws + 33751040);

    const int M = BB * NN;  // 65536

    knn_gather_prep_kernel<<<512, 1024, 0, stream>>>(xyz1, xyz2, feat2, interpB,
                                                     W1, W1pack, W2, W2pack);

    gemm_fused<<<M / GBM, 512, 0, stream>>>(feat1, interpB,
                                            W1pack, b1, W2pack, b2, out);
}

// Round 22
// 118.392 us; speedup vs baseline: 1.0508x; 1.0508x over previous
//
#include <hip/hip_runtime.h>
#include <hip/hip_bf16.h>

// Problem constants: B=8, N=8192, S=2048, C1=128, C2=256, OUT=256
#define BB   8
#define NN   8192
#define SS   2048
#define C1C  128
#define C2C  256
#define KIN  384
#define OUTC 256

typedef __attribute__((ext_vector_type(4))) float f32x4;
typedef __attribute__((ext_vector_type(8))) short short8;
typedef __attribute__((ext_vector_type(8))) unsigned short ushortx8;

__device__ __forceinline__ ushort f2bf(float v) {
    __hip_bfloat16 h = __float2bfloat16(v);
    return __builtin_bit_cast(ushort, h);
}

__device__ __forceinline__ float med3(float a, float b, float c) {
    return __builtin_amdgcn_fmed3f(a, b, c);
}

// x -> bucket quantizer: 256 bins over [-4,4], clamped; monotone
// non-decreasing, so a bucket range covers any x-interval.
__device__ __forceinline__ int xbucket(float x) {
    int b = (int)floorf((x + 4.0f) * 32.0f);
    return min(max(b, 0), 255);
}

// ---------------------------------------------------------------------------
// Fused 3-NN (x-bucket pruned, v2) + gather + weights prep.
// r21 post-mortem fixes: (1) points SORTED IN PLACE (ssp float4 + sid int)
// so window reads are contiguous, conflict-free, and unchained (r21's
// ssid->sp indirection caused 6.5M conflict cycles + a 2-hop dependent LDS
// chain); (2) points carried in registers through histogram->scatter;
// (3) window loop unrolled x2 with masked lanes; (4) window padded +-1
// bucket (0.03125 >> any fp slop) on top of the 1.001 sqrt margin.
// Selection = lex-min-3 of (f, orig idx) over a provable superset of the
// true top-3 == stable lax.top_k (order-invariant -> atomic-scatter
// nondeterminism harmless; same fmaf bits as the passing exhaustive scans).
// 1024 thr, 128 q/block, 512 blocks = 2 blocks/CU = 8 waves/SIMD.
// ---------------------------------------------------------------------------
__global__ __launch_bounds__(1024, 8) void knn_gather_prep_kernel(
    const float* __restrict__ xyz1, const float* __restrict__ xyz2,
    const float* __restrict__ feat2, ushort* __restrict__ interpB,
    const float* __restrict__ W1, ushort* __restrict__ W1pack,
    const float* __restrict__ W2, ushort* __restrict__ W2pack)
{
    __shared__ float4 ssp[SS];                    // 32 KB: points sorted by x
    __shared__ int    sid[SS];                    // 8 KB: orig index per slot
    __shared__ int    cnt[256];                   // hist -> inclusive prefix
    __shared__ int    cnt2[256];                  // scatter counters
    __shared__ int    sIdx[128][3];
    __shared__ float  sW[128][3];

    const int tid   = threadIdx.x;
    const int b     = blockIdx.x & 7;             // XCD-aligned batch
    const int chunk = blockIdx.x >> 3;            // 0..63
    const int qbase = chunk << 7;                 // 128 queries per block

    if (tid < 256) { cnt[tid] = 0; cnt2[tid] = 0; }
    __syncthreads();

    // ---- load 2 points/thread into registers, histogram ------------------
    const float* x2 = xyz2 + (size_t)b * SS * 3;
    float4 myP[2]; int myB[2];
#pragma unroll
    for (int t = 0; t < 2; ++t) {
        const int i = tid + t * 1024;
        float x = x2[i*3+0], y = x2[i*3+1], z = x2[i*3+2];
        myP[t] = make_float4(-2.f*x, -2.f*y, -2.f*z, x*x + y*y + z*z);
        myB[t] = xbucket(x);
        atomicAdd(&cnt[myB[t]], 1);
    }

    // ---- folded weights prep (r20, unchanged): 1 guarded elem/thread -----
    {
        const int idx = blockIdx.x * 1024 + tid;  // 0..524287
        const int n1 = 12 * 16 * 512;             // 98304 (W1pack)
        if (idx < n1) {
            int o = idx;
            int e = o & 7, lane = (o >> 3) & 63, j = (o >> 9) & 3;
            int wc = (o >> 11) & 3, s = o >> 13;
            int n = wc * 64 + j * 16 + (lane & 15);
            int k = s * 32 + (lane >> 4) * 8 + e;
            W1pack[o] = f2bf(W1[(size_t)k * OUTC + n]);
        } else if (idx < n1 + OUTC * OUTC) {
            int o = idx - n1;
            int e = o & 7, lane = (o >> 3) & 63, j = (o >> 9) & 3;
            int wc = (o >> 11) & 3, s = o >> 13;
            int n = wc * 64 + j * 16 + (lane & 15);
            int k = s * 32 + (lane >> 4) * 8 + e;
            W2pack[o] = f2bf(W2[(size_t)k * OUTC + n]);
        }
    }
    __syncthreads();

    // ---- inclusive prefix sum over 256 buckets (Hillis-Steele) -----------
    for (int d = 1; d < 256; d <<= 1) {
        int v = 0;
        if (tid < 256) {
            v = cnt[tid];
            if (tid >= d) v += cnt[tid - d];
        }
        __syncthreads();
        if (tid < 256) cnt[tid] = v;
        __syncthreads();
    }

    // ---- scatter: sorted point data + orig index -------------------------
#pragma unroll
    for (int t = 0; t < 2; ++t) {
        const int i = tid + t * 1024;
        int bq = myB[t];
        int base = (bq == 0) ? 0 : cnt[bq - 1];
        int pos = base + atomicAdd(&cnt2[bq], 1);
        ssp[pos] = myP[t];
        sid[pos] = i;
    }
    __syncthreads();

    const int g = tid >> 4;                       // 0..63 (query pair)
    const int l = tid & 15;                       // lane within query
    const int qa = qbase + g * 2;

    const float* qp = xyz1 + ((size_t)b * NN + qa) * 3;
    float pxa[2] = {qp[0], qp[3]};
    float pya[2] = {qp[1], qp[4]};
    float pza[2] = {qp[2], qp[5]};

#pragma unroll
    for (int qi = 0; qi < 2; ++qi) {
        const float px = pxa[qi], py = pya[qi], pz = pza[qi];
        const float n1 = px*px + py*py + pz*pz;

        // ---- seed: exact 3rd-best VALUE over 256 sorted slots ------------
        int cb = xbucket(px);
        int c  = (cb == 0) ? 0 : cnt[cb - 1];
        int sw0 = min(max(c - 128, 0), SS - 256);
        float a0 = 1e30f, a1 = 1e30f, a2 = 1e30f;
#pragma unroll
        for (int u = 0; u < 16; ++u) {
            float4 P = ssp[sw0 + u * 16 + l];
            float f = fmaf(px, P.x, fmaf(py, P.y, fmaf(pz, P.z, P.w)));
            a2 = med3(f, a1, a2);
            a1 = med3(f, a0, a1);
            a0 = fminf(f, a0);
        }
#pragma unroll
        for (int m = 1; m <= 8; m <<= 1) {
            float b0 = __shfl_xor(a0, m);
            float b1 = __shfl_xor(a1, m);
            float b2 = __shfl_xor(a2, m);
            float bv[3] = {b0, b1, b2};
#pragma unroll
            for (int e = 0; e < 3; ++e) {
                float d = bv[e];
                a2 = med3(d, a1, a2);
                a1 = med3(d, a0, a1);
                a0 = fminf(d, a0);
            }
        }

        // ---- window: buckets covering |x - px| <= rx, padded +-1 ---------
        float rx = sqrtf(fmaxf(a2 + n1, 0.f)) * 1.001f;
        int blo = max(xbucket(px - rx) - 1, 0);
        int bhi = min(xbucket(px + rx) + 1, 255);
        int lo2 = (blo == 0) ? 0 : cnt[blo - 1];
        int ub  = cnt[bhi];

        // ---- exact lex top-3 over the window (x2 unrolled, masked) -------
        float e0 = 1e30f, e1 = 1e30f, e2 = 1e30f;
        int   i0 = 0x3fffffff, i1 = 0x3fffffff, i2 = 0x3fffffff;
        for (int s0 = lo2; s0 < ub; s0 += 32) {
#pragma unroll
            for (int u = 0; u < 2; ++u) {
                int slot = s0 + u * 16 + l;
                bool valid = slot < ub;
                int sl = valid ? slot : (ub - 1);
                float4 P = ssp[sl];
                int o = sid[sl];
                float f = fmaf(px, P.x, fmaf(py, P.y, fmaf(pz, P.z, P.w)));
                f = valid ? f : 1e30f;
                bool lt2 = (f < e2) || (f == e2 && o < i2);
                bool lt1 = (f < e1) || (f == e1 && o < i1);
                bool lt0 = (f < e0) || (f == e0 && o < i0);
                float ne2 = lt1 ? e1 : (lt2 ? f : e2);
                int   ni2 = lt1 ? i1 : (lt2 ? o : i2);
                float ne1 = lt0 ? e0 : (lt1 ? f : e1);
                int   ni1 = lt0 ? i0 : (lt1 ? o : i1);
                float ne0 = lt0 ? f : e0;
                int   ni0 = lt0 ? o : i0;
                e2 = ne2; i2 = ni2; e1 = ne1; i1 = ni1; e0 = ne0; i0 = ni0;
            }
        }

        // lex merge across the 16-lane group
#pragma unroll
        for (int m = 1; m <= 8; m <<= 1) {
            float ob0 = __shfl_xor(e0, m), ob1 = __shfl_xor(e1, m), ob2 = __shfl_xor(e2, m);
            int   oj0 = __shfl_xor(i0, m), oj1 = __shfl_xor(i1, m), oj2 = __shfl_xor(i2, m);
            float dv[3] = {ob0, ob1, ob2}; int iv[3] = {oj0, oj1, oj2};
#pragma unroll
            for (int e = 0; e < 3; ++e) {
                float d = dv[e]; int s = iv[e];
                bool lt2 = (d < e2) || (d == e2 && s < i2);
                bool lt1 = (d < e1) || (d == e1 && s < i1);
                bool lt0 = (d < e0) || (d == e0 && s < i0);
                float ne2 = lt1 ? e1 : (lt2 ? d : e2);
                int   ni2 = lt1 ? i1 : (lt2 ? s : i2);
                float ne1 = lt0 ? e0 : (lt1 ? d : e1);
                int   ni1 = lt0 ? i0 : (lt1 ? s : i1);
                float ne0 = lt0 ? d : e0;
                int   ni0 = lt0 ? s : i0;
                e2 = ne2; i2 = ni2; e1 = ne1; i1 = ni1; e0 = ne0; i0 = ni0;
            }
        }

        if (l == 0) {
            float d0 = sqrtf(fmaxf(n1 + e0, 0.f));
            float d1 = sqrtf(fmaxf(n1 + e1, 0.f));
            float d2s = sqrtf(fmaxf(n1 + e2, 0.f));
            float w0v = 1.f / fmaxf(d0, 1e-10f);
            float w1v = 1.f / fmaxf(d1, 1e-10f);
            float w2v = 1.f / fmaxf(d2s, 1e-10f);
            float wsum = w0v + w1v + w2v;
            int qq = g * 2 + qi;
            sIdx[qq][0] = i0; sIdx[qq][1] = i1; sIdx[qq][2] = i2;
            sW[qq][0] = w0v / wsum; sW[qq][1] = w1v / wsum; sW[qq][2] = w2v / wsum;
        }
    }
    __syncthreads();

    // gather phase: wave wid handles queries wid, wid+16, ... (coalesced rows)
    const int wid = tid >> 6, lane = tid & 63;
    for (int qq = wid; qq < 128; qq += 16) {
        int a0 = sIdx[qq][0], a1 = sIdx[qq][1], a2 = sIdx[qq][2];
        float w0 = sW[qq][0], w1 = sW[qq][1], w2 = sW[qq][2];
        const float4* r0 = (const float4*)(feat2 + ((size_t)b * SS + a0) * C2C);
        const float4* r1 = (const float4*)(feat2 + ((size_t)b * SS + a1) * C2C);
        const float4* r2 = (const float4*)(feat2 + ((size_t)b * SS + a2) * C2C);
        float4 v0 = r0[lane], v1 = r1[lane], v2 = r2[lane];
        ushort4 o;
        o.x = f2bf(w0*v0.x + w1*v1.x + w2*v2.x);
        o.y = f2bf(w0*v0.y + w1*v1.y + w2*v2.y);
        o.z = f2bf(w0*v0.z + w1*v1.z + w2*v2.z);
        o.w = f2bf(w0*v0.w + w1*v1.w + w2*v2.w);
        *(ushort4*)(interpB + ((size_t)b * NN + qbase + qq) * C2C + lane * 4) = o;
    }
}

// ---------------------------------------------------------------------------
// FUSED two-layer MFMA GEMM (EXACT r20, measured best):
//   out = relu(relu([feat1|interpB]@W1^T + b1)@W2^T + b2), H in LDS only.
// Phase 1: A-only LDS dbuf + register-B from W1pack. Phase 2: register-B
// from W2pack, barrier-free.
// ---------------------------------------------------------------------------
#define GBM 128
#define GBN 256
#define GBK 32

__device__ __forceinline__ void gld_lds16(const void* g, void* l) {
    __builtin_amdgcn_global_load_lds(
        (const __attribute__((address_space(1))) void*)g,
        (__attribute__((address_space(3))) void*)l, 16, 0, 0);
}

__global__ __launch_bounds__(512, 4) void gemm_fused(
    const float* __restrict__ feat1,
    const ushort* __restrict__ interpB,
    const ushort* __restrict__ W1pack, const float* __restrict__ b1,
    const ushort* __restrict__ W2pack, const float* __restrict__ b2,
    float* __restrict__ out)
{
    __shared__ ushort pool[GBM * 256];   // 64 KB: phase1 A-dbuf (2x8KB); then H

    const int tid  = threadIdx.x;
    const int lane = tid & 63;
    const int wid  = tid >> 6;           // 0..7
    const int m0   = blockIdx.x * GBM;
    const int wr   = wid >> 2;           // 0..1
    const int wc   = wid & 3;            // 0..3

    const int rsub = lane >> 2;                    // 0..15 (row in 16-row chunk)
    const int slot = lane & 3;                     // 0..3  (8-ushort slot)
    const int csub = slot * 8;                     // linear LDS slot offset
    const int usw  = (slot ^ (rsub & 3)) * 8;      // swizzled SOURCE slot offset

    const int kgrp = (lane >> 4) * 8;
    const int rl   = lane & 15;
    const int ksw  = kgrp ^ ((rl & 3) << 3);       // swizzled read slot
    const int cl   = lane & 15;
    const int rgrp = (lane >> 4) * 4;

    // stage one K-step of A only: each wave stages its own 16-row chunk.
    auto stageA = [&](int k0, int buf) {
        ushort* sAb = pool + buf * 4096;           // 8KB buffer
        const int r = m0 + wid * 16 + rsub;
        if (k0 < C1C) {
            const float* src = feat1 + (size_t)r * C1C + k0 + usw;
            float4 u = ((const float4*)src)[0];
            float4 v = ((const float4*)src)[1];
            ushortx8 t;
            t[0] = f2bf(u.x); t[1] = f2bf(u.y); t[2] = f2bf(u.z); t[3] = f2bf(u.w);
            t[4] = f2bf(v.x); t[5] = f2bf(v.y); t[6] = f2bf(v.z); t[7] = f2bf(v.w);
            *(ushortx8*)&sAb[wid * 512 + rsub * 32 + csub] = t;
        } else {
            gld_lds16(interpB + (size_t)r * C2C + (k0 - C1C) + usw, &sAb[wid * 512]);
        }
    };

    // ---------------- phase 1: acc1 = A @ W1^T (A-dbuf + register B) -------
    f32x4 acc1[4][4];
#pragma unroll
    for (int i = 0; i < 4; ++i)
#pragma unroll
        for (int j = 0; j < 4; ++j) acc1[i][j] = (f32x4){0.f, 0.f, 0.f, 0.f};

    int cur = 0;
    stageA(0, 0);
    short8 bfc[4], bfn[4];
#pragma unroll
    for (int j = 0; j < 4; ++j)
        bfc[j] = *(const short8*)&W1pack[(size_t)(0 * 16 + wc * 4 + j) * 512 + lane * 8];

    for (int k0 = 0, s = 0; k0 < KIN; k0 += GBK, ++s) {
        __syncthreads();                 // stage(k0->cur) done; prev reads done
        if (k0 + GBK < KIN) {
            stageA(k0 + GBK, cur ^ 1);
#pragma unroll
            for (int j = 0; j < 4; ++j)
                bfn[j] = *(const short8*)&W1pack[(size_t)((s + 1) * 16 + wc * 4 + j) * 512 + lane * 8];
        }

        const ushort* sAb = pool + cur * 4096;
        short8 af[4];
#pragma unroll
        for (int i = 0; i < 4; ++i)
            af[i] = *(const short8*)&sAb[(wr * 64 + i * 16 + rl) * GBK + ksw];
#pragma unroll
        for (int i = 0; i < 4; ++i)
#pragma unroll
            for (int j = 0; j < 4; ++j)
                acc1[i][j] = __builtin_amdgcn_mfma_f32_16x16x32_bf16(
                    af[i], bfc[j], acc1[i][j], 0, 0, 0);
#pragma unroll
        for (int j = 0; j < 4; ++j) bfc[j] = bfn[j];
        cur ^= 1;
    }
    __syncthreads();                     // all phase-1 LDS reads done (pool reuse)

    // issue phase-2 first B-frags early (hide L2 latency under H writes)
#pragma unroll
    for (int j = 0; j < 4; ++j)
        bfc[j] = *(const short8*)&W2pack[(size_t)(0 * 16 + wc * 4 + j) * 512 + lane * 8];

    // ---------------- transition: H = relu(acc1+b1) -> LDS (bf16) ----------
#pragma unroll
    for (int j = 0; j < 4; ++j) {
        const int c = wc * 64 + j * 16 + cl;
        const float bv = b1[c];
        const int u = c >> 3, sub = c & 7;
#pragma unroll
        for (int i = 0; i < 4; ++i) {
#pragma unroll
            for (int rr = 0; rr < 4; ++rr) {
                const int r = wr * 64 + i * 16 + rgrp + rr;
                const float v = fmaxf(acc1[i][j][rr] + bv, 0.f);
                pool[r * 256 + ((u ^ (r & 31)) << 3) + sub] = f2bf(v);
            }
        }
    }
    __syncthreads();                     // H complete

    // ---------------- phase 2: out = relu(H @ W2^T + b2), barrier-free -----
    f32x4 acc2[4][4];
#pragma unroll
    for (int i = 0; i < 4; ++i)
#pragma unroll
        for (int j = 0; j < 4; ++j) acc2[i][j] = (f32x4){0.f, 0.f, 0.f, 0.f};

    for (int s = 0; s < 8; ++s) {
        if (s < 7) {
#pragma unroll
            for (int j = 0; j < 4; ++j)
                bfn[j] = *(const short8*)&W2pack[(size_t)((s + 1) * 16 + wc * 4 + j) * 512 + lane * 8];
        }
        const int ub = s * 4 + (lane >> 4);        // H unit index 0..31
        short8 af[4];
#pragma unroll
        for (int i = 0; i < 4; ++i) {
            const int r = wr * 64 + i * 16 + rl;
            af[i] = *(const short8*)&pool[r * 256 + ((ub ^ (r & 31)) << 3)];
        }
#pragma unroll
        for (int i = 0; i < 4; ++i)
#pragma unroll
            for (int j = 0; j < 4; ++j)
                acc2[i][j] = __builtin_amdgcn_mfma_f32_16x16x32_bf16(
                    af[i], bfc[j], acc2[i][j], 0, 0, 0);
#pragma unroll
        for (int j = 0; j < 4; ++j) bfc[j] = bfn[j];
    }

    // ---------------- epilogue: bias + relu -> f32 out ---------------------
#pragma unroll
    for (int j = 0; j < 4; ++j) {
        const int col = wc * 64 + j * 16 + cl;
        const float bv = b2[col];
#pragma unroll
        for (int i = 0; i < 4; ++i) {
            const int rowb = m0 + wr * 64 + i * 16 + rgrp;
#pragma unroll
            for (int rr = 0; rr < 4; ++rr) {
                out[(size_t)(rowb + rr) * OUTC + col] =
                    fmaxf(acc2[i][j][rr] + bv, 0.f);
            }
        }
    }
}

// ---------------------------------------------------------------------------
// ws layout (bytes): interpB 33.5M @0 | W1pack 192K @33554432
// | W2pack 128K @33751040
// ---------------------------------------------------------------------------
extern "C" void kernel_launch(void* const* d_in, const int* in_sizes, int n_in,
                              void* d_out, int out_size, void* d_ws, size_t ws_size,
                              hipStream_t stream) {
    const float* xyz1  = (const float*)d_in[0];
    const float* xyz2  = (const float*)d_in[1];
    const float* feat1 = (const float*)d_in[2];
    const float* feat2 = (const float*)d_in[3];
    const float* W1    = (const float*)d_in[4];
    const float* b1    = (const float*)d_in[5];
    const float* W2    = (const float*)d_in[6];
    const float* b2    = (const float*)d_in[7];
    float* out = (float*)d_out;

    char* ws = (char*)d_ws;
    ushort* interpB = (ushort*)(ws);
    ushort* W1pack  = (ushort*)(ws + 33554432);
    ushort* W2pack  = (ushort*)(ws + 33751040);

    const int M = BB * NN;  // 65536

    knn_gather_prep_kernel<<<512, 1024, 0, stream>>>(xyz1, xyz2, feat2, interpB,
                                                     W1, W1pack, W2, W2pack);

    gemm_fused<<<M / GBM, 512, 0, stream>>>(feat1, interpB,
                                            W1pack, b1, W2pack, b2, out);
}

// Round 23
// 97.362 us; speedup vs baseline: 1.2778x; 1.2160x over previous
//
#include <hip/hip_runtime.h>
#include <hip/hip_bf16.h>

// Problem constants: B=8, N=8192, S=2048, C1=128, C2=256, OUT=256
#define BB   8
#define NN   8192
#define SS   2048
#define C1C  128
#define C2C  256
#define KIN  384
#define OUTC 256

typedef __attribute__((ext_vector_type(4))) float f32x4;
typedef __attribute__((ext_vector_type(8))) short short8;
typedef __attribute__((ext_vector_type(8))) unsigned short ushortx8;

__device__ __forceinline__ ushort f2bf(float v) {
    __hip_bfloat16 h = __float2bfloat16(v);
    return __builtin_bit_cast(ushort, h);
}

__device__ __forceinline__ float med3(float a, float b, float c) {
    return __builtin_amdgcn_fmed3f(a, b, c);
}

// ---------------------------------------------------------------------------
// Fused 3-NN scan + gather + weights prep (EXACT r20, measured best 97.7us
// total). Exhaustive two-pass scan: its fully static, unrolled,
// conflict-free structure sustains ~84% VALU issue at 8 waves/SIMD —
// measured faster than every pruned/packed/restructured variant (r7, r17,
// r18, r21, r22 all regressed).
// L=16 lanes/query, Q=2 queries/thread, 128 queries/block, 1024 threads,
// grid 512 = 2 blocks/CU = 8 waves/SIMD.
// ---------------------------------------------------------------------------
__global__ __launch_bounds__(1024, 8) void knn_gather_prep_kernel(
    const float* __restrict__ xyz1, const float* __restrict__ xyz2,
    const float* __restrict__ feat2, ushort* __restrict__ interpB,
    const float* __restrict__ W1, ushort* __restrict__ W1pack,
    const float* __restrict__ W2, ushort* __restrict__ W2pack)
{
    __shared__ float4 sp[SS];                     // 32 KB
    __shared__ int   sIdx[128][3];
    __shared__ float sW[128][3];

    const int tid   = threadIdx.x;
    const int b     = blockIdx.x & 7;             // XCD-aligned batch
    const int chunk = blockIdx.x >> 3;            // 0..63
    const int qbase = chunk << 7;                 // 128 queries per block

    const float* x2 = xyz2 + (size_t)b * SS * 3;
    for (int i = tid; i < SS; i += 1024) {
        float x = x2[i*3+0], y = x2[i*3+1], z = x2[i*3+2];
        sp[i] = make_float4(-2.f*x, -2.f*y, -2.f*z, x*x + y*y + z*z);
    }

    // ---- folded weights prep: one guarded element per thread --------------
    // W1pack/W2pack layout: [s][wc][j][lane][e], elem = W[k][n] with
    // n = wc*64+j*16+(lane&15), k = s*32+(lane>>4)*8+e.
    {
        const int idx = blockIdx.x * 1024 + tid;  // 0..524287
        const int n1 = 12 * 16 * 512;             // 98304 (W1pack, s=0..11)
        if (idx < n1) {
            int o = idx;
            int e = o & 7, lane = (o >> 3) & 63, j = (o >> 9) & 3;
            int wc = (o >> 11) & 3, s = o >> 13;
            int n = wc * 64 + j * 16 + (lane & 15);
            int k = s * 32 + (lane >> 4) * 8 + e;
            W1pack[o] = f2bf(W1[(size_t)k * OUTC + n]);
        } else if (idx < n1 + OUTC * OUTC) {
            int o = idx - n1;
            int e = o & 7, lane = (o >> 3) & 63, j = (o >> 9) & 3;
            int wc = (o >> 11) & 3, s = o >> 13;
            int n = wc * 64 + j * 16 + (lane & 15);
            int k = s * 32 + (lane >> 4) * 8 + e;
            W2pack[o] = f2bf(W2[(size_t)k * OUTC + n]);
        }
    }
    __syncthreads();

    const int g = tid >> 4;                       // 0..63 (query pair)
    const int l = tid & 15;                       // lane within query
    const int qa = qbase + g * 2;

    const float* qp = xyz1 + ((size_t)b * NN + qa) * 3;
    float px[2] = {qp[0], qp[3]};
    float py[2] = {qp[1], qp[4]};
    float pz[2] = {qp[2], qp[5]};

    // ---------------- pass 1: top-3 values, branchless ----------------
    float c0[2], c1[2], c2[2];
#pragma unroll
    for (int qi = 0; qi < 2; ++qi) { c0[qi] = c1[qi] = c2[qi] = 1e30f; }

    for (int jj = 0; jj < 128; jj += 4) {
        float4 P[4];
#pragma unroll
        for (int u = 0; u < 4; ++u) P[u] = sp[((jj + u) << 4) + l];
#pragma unroll
        for (int u = 0; u < 4; ++u) {
#pragma unroll
            for (int qi = 0; qi < 2; ++qi) {
                float f = fmaf(px[qi], P[u].x,
                          fmaf(py[qi], P[u].y,
                          fmaf(pz[qi], P[u].z, P[u].w)));
                c2[qi] = med3(f, c1[qi], c2[qi]);
                c1[qi] = med3(f, c0[qi], c1[qi]);
                c0[qi] = fminf(f, c0[qi]);
            }
        }
    }

    // value-merge across the 16-lane group (multiset union top-3)
#pragma unroll
    for (int m = 1; m <= 8; m <<= 1) {
#pragma unroll
        for (int qi = 0; qi < 2; ++qi) {
            float b0 = __shfl_xor(c0[qi], m);
            float b1 = __shfl_xor(c1[qi], m);
            float b2 = __shfl_xor(c2[qi], m);
            float bv[3] = {b0, b1, b2};
#pragma unroll
            for (int e = 0; e < 3; ++e) {
                float d = bv[e];
                c2[qi] = med3(d, c1[qi], c2[qi]);
                c1[qi] = med3(d, c0[qi], c1[qi]);
                c0[qi] = fminf(d, c0[qi]);
            }
        }
    }
    const float t0 = c2[0], t1 = c2[1];           // exact 3rd-smallest scores

    // ---------------- pass 2: index recovery (rare inserts) ----------------
    float e0[2], e1[2], e2[2];
    int   i0[2], i1[2], i2[2];
#pragma unroll
    for (int qi = 0; qi < 2; ++qi) {
        e0[qi] = e1[qi] = e2[qi] = 1e30f;
        i0[qi] = i1[qi] = i2[qi] = 0x3fffffff;
    }

    for (int jj = 0; jj < 128; jj += 4) {
        float4 P[4];
#pragma unroll
        for (int u = 0; u < 4; ++u) P[u] = sp[((jj + u) << 4) + l];
#pragma unroll
        for (int u = 0; u < 4; ++u) {
            const int s = ((jj + u) << 4) + l;
#pragma unroll
            for (int qi = 0; qi < 2; ++qi) {
                float f = fmaf(px[qi], P[u].x,
                          fmaf(py[qi], P[u].y,
                          fmaf(pz[qi], P[u].z, P[u].w)));
                float tq = qi ? t1 : t0;
                if (f <= tq) {                     // ~3 hits per query total
                    bool lt2 = (f < e2[qi]) || (f == e2[qi] && s < i2[qi]);
                    if (lt2) {
                        bool lt1 = (f < e1[qi]) || (f == e1[qi] && s < i1[qi]);
                        bool lt0 = (f < e0[qi]) || (f == e0[qi] && s < i0[qi]);
                        e2[qi] = lt1 ? e1[qi] : f;  i2[qi] = lt1 ? i1[qi] : s;
                        e1[qi] = lt0 ? e0[qi] : (lt1 ? f : e1[qi]);
                        i1[qi] = lt0 ? i0[qi] : (lt1 ? s : i1[qi]);
                        e0[qi] = lt0 ? f : e0[qi];  i0[qi] = lt0 ? s : i0[qi];
                    }
                }
            }
        }
    }

    // lex merge across the 16-lane group
#pragma unroll
    for (int m = 1; m <= 8; m <<= 1) {
#pragma unroll
        for (int qi = 0; qi < 2; ++qi) {
            float ob0 = __shfl_xor(e0[qi], m), ob1 = __shfl_xor(e1[qi], m), ob2 = __shfl_xor(e2[qi], m);
            int   oj0 = __shfl_xor(i0[qi], m), oj1 = __shfl_xor(i1[qi], m), oj2 = __shfl_xor(i2[qi], m);
            float dv[3] = {ob0, ob1, ob2}; int iv[3] = {oj0, oj1, oj2};
#pragma unroll
            for (int e = 0; e < 3; ++e) {
                float d = dv[e]; int s = iv[e];
                bool lt2 = (d < e2[qi]) || (d == e2[qi] && s < i2[qi]);
                if (lt2) {
                    bool lt1 = (d < e1[qi]) || (d == e1[qi] && s < i1[qi]);
                    bool lt0 = (d < e0[qi]) || (d == e0[qi] && s < i0[qi]);
                    e2[qi] = lt1 ? e1[qi] : d;  i2[qi] = lt1 ? i1[qi] : s;
                    e1[qi] = lt0 ? e0[qi] : (lt1 ? d : e1[qi]);
                    i1[qi] = lt0 ? i0[qi] : (lt1 ? s : i1[qi]);
                    e0[qi] = lt0 ? d : e0[qi];  i0[qi] = lt0 ? s : i0[qi];
                }
            }
        }
    }

    if (l == 0) {
#pragma unroll
        for (int qi = 0; qi < 2; ++qi) {
            float nx = px[qi], ny = py[qi], nz = pz[qi];
            float n1 = nx*nx + ny*ny + nz*nz;
            float d0 = sqrtf(fmaxf(n1 + e0[qi], 0.f));
            float d1 = sqrtf(fmaxf(n1 + e1[qi], 0.f));
            float d2s = sqrtf(fmaxf(n1 + e2[qi], 0.f));
            float w0 = 1.f / fmaxf(d0, 1e-10f);
            float w1 = 1.f / fmaxf(d1, 1e-10f);
            float w2 = 1.f / fmaxf(d2s, 1e-10f);
            float wsum = w0 + w1 + w2;
            int qq = g * 2 + qi;
            sIdx[qq][0] = i0[qi]; sIdx[qq][1] = i1[qi]; sIdx[qq][2] = i2[qi];
            sW[qq][0] = w0 / wsum; sW[qq][1] = w1 / wsum; sW[qq][2] = w2 / wsum;
        }
    }
    __syncthreads();

    // gather phase: wave wid handles queries wid, wid+16, ... (coalesced rows)
    const int wid = tid >> 6, lane = tid & 63;
    for (int qq = wid; qq < 128; qq += 16) {
        int a0 = sIdx[qq][0], a1 = sIdx[qq][1], a2 = sIdx[qq][2];
        float w0 = sW[qq][0], w1 = sW[qq][1], w2 = sW[qq][2];
        const float4* r0 = (const float4*)(feat2 + ((size_t)b * SS + a0) * C2C);
        const float4* r1 = (const float4*)(feat2 + ((size_t)b * SS + a1) * C2C);
        const float4* r2 = (const float4*)(feat2 + ((size_t)b * SS + a2) * C2C);
        float4 v0 = r0[lane], v1 = r1[lane], v2 = r2[lane];
        ushort4 o;
        o.x = f2bf(w0*v0.x + w1*v1.x + w2*v2.x);
        o.y = f2bf(w0*v0.y + w1*v1.y + w2*v2.y);
        o.z = f2bf(w0*v0.z + w1*v1.z + w2*v2.z);
        o.w = f2bf(w0*v0.w + w1*v1.w + w2*v2.w);
        *(ushort4*)(interpB + ((size_t)b * NN + qbase + qq) * C2C + lane * 4) = o;
    }
}

// ---------------------------------------------------------------------------
// FUSED two-layer MFMA GEMM (EXACT r20, measured best):
//   out = relu(relu([feat1|interpB]@W1^T + b1)@W2^T + b2), H in LDS only.
// Phase 1: A-only LDS dbuf + register-B from W1pack. Phase 2: register-B
// from W2pack, barrier-free.
// ---------------------------------------------------------------------------
#define GBM 128
#define GBN 256
#define GBK 32

__device__ __forceinline__ void gld_lds16(const void* g, void* l) {
    __builtin_amdgcn_global_load_lds(
        (const __attribute__((address_space(1))) void*)g,
        (__attribute__((address_space(3))) void*)l, 16, 0, 0);
}

__global__ __launch_bounds__(512, 4) void gemm_fused(
    const float* __restrict__ feat1,
    const ushort* __restrict__ interpB,
    const ushort* __restrict__ W1pack, const float* __restrict__ b1,
    const ushort* __restrict__ W2pack, const float* __restrict__ b2,
    float* __restrict__ out)
{
    __shared__ ushort pool[GBM * 256];   // 64 KB: phase1 A-dbuf (2x8KB); then H

    const int tid  = threadIdx.x;
    const int lane = tid & 63;
    const int wid  = tid >> 6;           // 0..7
    const int m0   = blockIdx.x * GBM;
    const int wr   = wid >> 2;           // 0..1
    const int wc   = wid & 3;            // 0..3

    const int rsub = lane >> 2;                    // 0..15 (row in 16-row chunk)
    const int slot = lane & 3;                     // 0..3  (8-ushort slot)
    const int csub = slot * 8;                     // linear LDS slot offset
    const int usw  = (slot ^ (rsub & 3)) * 8;      // swizzled SOURCE slot offset

    const int kgrp = (lane >> 4) * 8;
    const int rl   = lane & 15;
    const int ksw  = kgrp ^ ((rl & 3) << 3);       // swizzled read slot
    const int cl   = lane & 15;
    const int rgrp = (lane >> 4) * 4;

    // stage one K-step of A only: each wave stages its own 16-row chunk.
    auto stageA = [&](int k0, int buf) {
        ushort* sAb = pool + buf * 4096;           // 8KB buffer
        const int r = m0 + wid * 16 + rsub;
        if (k0 < C1C) {
            const float* src = feat1 + (size_t)r * C1C + k0 + usw;
            float4 u = ((const float4*)src)[0];
            float4 v = ((const float4*)src)[1];
            ushortx8 t;
            t[0] = f2bf(u.x); t[1] = f2bf(u.y); t[2] = f2bf(u.z); t[3] = f2bf(u.w);
            t[4] = f2bf(v.x); t[5] = f2bf(v.y); t[6] = f2bf(v.z); t[7] = f2bf(v.w);
            *(ushortx8*)&sAb[wid * 512 + rsub * 32 + csub] = t;
        } else {
            gld_lds16(interpB + (size_t)r * C2C + (k0 - C1C) + usw, &sAb[wid * 512]);
        }
    };

    // ---------------- phase 1: acc1 = A @ W1^T (A-dbuf + register B) -------
    f32x4 acc1[4][4];
#pragma unroll
    for (int i = 0; i < 4; ++i)
#pragma unroll
        for (int j = 0; j < 4; ++j) acc1[i][j] = (f32x4){0.f, 0.f, 0.f, 0.f};

    int cur = 0;
    stageA(0, 0);
    short8 bfc[4], bfn[4];
#pragma unroll
    for (int j = 0; j < 4; ++j)
        bfc[j] = *(const short8*)&W1pack[(size_t)(0 * 16 + wc * 4 + j) * 512 + lane * 8];

    for (int k0 = 0, s = 0; k0 < KIN; k0 += GBK, ++s) {
        __syncthreads();                 // stage(k0->cur) done; prev reads done
        if (k0 + GBK < KIN) {
            stageA(k0 + GBK, cur ^ 1);
#pragma unroll
            for (int j = 0; j < 4; ++j)
                bfn[j] = *(const short8*)&W1pack[(size_t)((s + 1) * 16 + wc * 4 + j) * 512 + lane * 8];
        }

        const ushort* sAb = pool + cur * 4096;
        short8 af[4];
#pragma unroll
        for (int i = 0; i < 4; ++i)
            af[i] = *(const short8*)&sAb[(wr * 64 + i * 16 + rl) * GBK + ksw];
#pragma unroll
        for (int i = 0; i < 4; ++i)
#pragma unroll
            for (int j = 0; j < 4; ++j)
                acc1[i][j] = __builtin_amdgcn_mfma_f32_16x16x32_bf16(
                    af[i], bfc[j], acc1[i][j], 0, 0, 0);
#pragma unroll
        for (int j = 0; j < 4; ++j) bfc[j] = bfn[j];
        cur ^= 1;
    }
    __syncthreads();                     // all phase-1 LDS reads done (pool reuse)

    // issue phase-2 first B-frags early (hide L2 latency under H writes)
#pragma unroll
    for (int j = 0; j < 4; ++j)
        bfc[j] = *(const short8*)&W2pack[(size_t)(0 * 16 + wc * 4 + j) * 512 + lane * 8];

    // ---------------- transition: H = relu(acc1+b1) -> LDS (bf16) ----------
#pragma unroll
    for (int j = 0; j < 4; ++j) {
        const int c = wc * 64 + j * 16 + cl;
        const float bv = b1[c];
        const int u = c >> 3, sub = c & 7;
#pragma unroll
        for (int i = 0; i < 4; ++i) {
#pragma unroll
            for (int rr = 0; rr < 4; ++rr) {
                const int r = wr * 64 + i * 16 + rgrp + rr;
                const float v = fmaxf(acc1[i][j][rr] + bv, 0.f);
                pool[r * 256 + ((u ^ (r & 31)) << 3) + sub] = f2bf(v);
            }
        }
    }
    __syncthreads();                     // H complete

    // ---------------- phase 2: out = relu(H @ W2^T + b2), barrier-free -----
    f32x4 acc2[4][4];
#pragma unroll
    for (int i = 0; i < 4; ++i)
#pragma unroll
        for (int j = 0; j < 4; ++j) acc2[i][j] = (f32x4){0.f, 0.f, 0.f, 0.f};

    for (int s = 0; s < 8; ++s) {
        if (s < 7) {
#pragma unroll
            for (int j = 0; j < 4; ++j)
                bfn[j] = *(const short8*)&W2pack[(size_t)((s + 1) * 16 + wc * 4 + j) * 512 + lane * 8];
        }
        const int ub = s * 4 + (lane >> 4);        // H unit index 0..31
        short8 af[4];
#pragma unroll
        for (int i = 0; i < 4; ++i) {
            const int r = wr * 64 + i * 16 + rl;
            af[i] = *(const short8*)&pool[r * 256 + ((ub ^ (r & 31)) << 3)];
        }
#pragma unroll
        for (int i = 0; i < 4; ++i)
#pragma unroll
            for (int j = 0; j < 4; ++j)
                acc2[i][j] = __builtin_amdgcn_mfma_f32_16x16x32_bf16(
                    af[i], bfc[j], acc2[i][j], 0, 0, 0);
#pragma unroll
        for (int j = 0; j < 4; ++j) bfc[j] = bfn[j];
    }

    // ---------------- epilogue: bias + relu -> f32 out ---------------------
#pragma unroll
    for (int j = 0; j < 4; ++j) {
        const int col = wc * 64 + j * 16 + cl;
        const float bv = b2[col];
#pragma unroll
        for (int i = 0; i < 4; ++i) {
            const int rowb = m0 + wr * 64 + i * 16 + rgrp;
#pragma unroll
            for (int rr = 0; rr < 4; ++rr) {
                out[(size_t)(rowb + rr) * OUTC + col] =
                    fmaxf(acc2[i][j][rr] + bv, 0.f);
            }
        }
    }
}

// ---------------------------------------------------------------------------
// ws layout (bytes): interpB 33.5M @0 | W1pack 192K @33554432
// | W2pack 128K @33751040
// ---------------------------------------------------------------------------
extern "C" void kernel_launch(void* const* d_in, const int* in_sizes, int n_in,
                              void* d_out, int out_size, void* d_ws, size_t ws_size,
                              hipStream_t stream) {
    const float* xyz1  = (const float*)d_in[0];
    const float* xyz2  = (const float*)d_in[1];
    const float* feat1 = (const float*)d_in[2];
    const float* feat2 = (const float*)d_in[3];
    const float* W1    = (const float*)d_in[4];
    const float* b1    = (const float*)d_in[5];
    const float* W2    = (const float*)d_in[6];
    const float* b2    = (const float*)d_in[7];
    float* out = (float*)d_out;

    char* ws = (char*)d_ws;
    ushort* interpB = (ushort*)(ws);
    ushort* W1pack  = (ushort*)(ws + 33554432);
    ushort* W2pack  = (ushort*)(ws + 33751040);

    const int M = BB * NN;  // 65536

    knn_gather_prep_kernel<<<512, 1024, 0, stream>>>(xyz1, xyz2, feat2, interpB,
                                                     W1, W1pack, W2, W2pack);

    gemm_fused<<<M / GBM, 512, 0, stream>>>(feat1, interpB,
                                            W1pack, b1, W2pack, b2, out);
}